// Round 7
// baseline (197.084 us; speedup 1.0000x reference)
//
#include <hip/hip_runtime.h>
#include <hip/hip_bf16.h>

// Conv2d 3x3 pad=1 stride=1, B=32, 256->256, 56x56, fp32 in/out.
// Implicit GEMM. Block 128co x 128px, 4 waves (wave tile 64x64), BK=32,
// 16x16x32 MFMA. A fragment-packed, global->VGPR distance-1 (L2-resident);
// B staged via global_load_lds into a RING-4 (distance-3 stage, vmcnt(12) =
// two bodies of slack -> B-stage has ~1600+ cy to land vs ~900 cy HBM
// latency). 32KB LDS, 72 VGPR -> up to 4 blocks/CU. 1 barrier/K-tile.

#define BB    32
#define CINC  256
#define COUTC 256
#define HH    56
#define WW    56
#define HP    58
#define WP    58
#define PIX_PER_IMG 3136
#define NPIX  100352
#define KTOT  2304
#define NKT   72                     // K-tiles of 32

#define XT_BYTES ((size_t)BB*HP*WP*CINC*2)
#define AWR_FRAGS (72*16*64)         // (t, mb, lane) 16B frags
#define AWR_BYTES ((size_t)AWR_FRAGS*16)

#define BUF_SZ 8192                  // B: 128 rows x 64B

using frag_t = __attribute__((ext_vector_type(8))) short;   // 8 bf16
using f32x4  = __attribute__((ext_vector_type(4))) float;

__device__ __forceinline__ void gload_lds16(const void* gsrc, void* ldst) {
  __builtin_amdgcn_global_load_lds(
      (const __attribute__((address_space(1))) unsigned*)gsrc,
      (__attribute__((address_space(3))) unsigned*)ldst, 16, 0, 0);
}

// ---------- pre-pass 1: NCHW fp32 -> padded channels-last bf16 Xt[b][58][58][256]
__global__ void xpose_kernel(const float* __restrict__ inp,
                             __hip_bfloat16* __restrict__ xt) {
  int bid = blockIdx.x;
  int hp = bid % HP;
  int t  = bid / HP;
  int cb = t % 4;
  int b  = t / 4;
  __shared__ __hip_bfloat16 tile[64 * 60];
  int tid = threadIdx.x;
  for (int i = tid; i < 64 * 60; i += 256) tile[i] = __float2bfloat16(0.f);
  __syncthreads();
  int h = hp - 1;
  if (h >= 0 && h < HH) {
    const float* src = inp + ((size_t)(b * CINC + cb * 64) * HH + h) * WW;
    for (int i = tid; i < 64 * WW; i += 256) {
      int ci = i / WW, w = i - ci * WW;
      tile[ci * 60 + (w + 1)] = __float2bfloat16(src[(size_t)ci * HH * WW + w]);
    }
  }
  __syncthreads();
  __hip_bfloat16* dst = xt + ((size_t)(b * HP + hp) * WP) * CINC + cb * 64;
  for (int i = tid; i < WP * 64; i += 256) {
    int wp = i >> 6, ci = i & 63;
    dst[(size_t)wp * CINC + ci] = tile[ci * 60 + wp];
  }
}

// ---------- pre-pass 2: OIHW fp32 -> fragment-ordered Awr[t][mb][lane] (16B)
// lane l of frag (t, mb) holds A[co = mb*16 + (l&15)][k = t*32 + (l>>4)*8 + j]
__global__ void wprep_pack(const float* __restrict__ k4,
                           frag_t* __restrict__ awr) {
  int i = blockIdx.x * 256 + threadIdx.x;   // (t*16 + mb)*64 + lane
  if (i >= AWR_FRAGS) return;
  int lane = i & 63;
  int mb   = (i >> 6) & 15;
  int t    = i >> 10;
  int co   = mb * 16 + (lane & 15);
  int kb   = t * 32 + (lane >> 4) * 8;
  frag_t v;
#pragma unroll
  for (int j = 0; j < 8; ++j) {
    int k = kb + j;
    int tap = k >> 8;
    int ci  = k & 255;
    __hip_bfloat16 h = __float2bfloat16(k4[(co * CINC + ci) * 9 + tap]);
    v[j] = *reinterpret_cast<short*>(&h);
  }
  awr[i] = v;
}

// ---------- main kernel
__global__ __launch_bounds__(256, 4) void conv_ring4(
    const __hip_bfloat16* __restrict__ xt,
    const frag_t* __restrict__ awr,
    const float* __restrict__ bias,
    float* __restrict__ out) {
  __shared__ alignas(16) char lds[4 * BUF_SZ];   // 32 KiB ring-4

  const int tid  = threadIdx.x;
  const int lane = tid & 63;
  const int wid  = tid >> 6;          // 0..3
  const int wm   = wid >> 1;          // co half of block (0/1): rows wm*64
  const int wn   = wid & 1;           // px half of block (0/1): cols wn*64
  const int fr   = lane & 15;
  const int g    = lane >> 4;         // 0..3 k-chunk

  // grid 1568 = 8 * 196, bijective XCD swizzle; interleave co-tiles so both
  // co halves of a px panel land on the same XCD (B L2 reuse).
  const int bid   = blockIdx.x;
  const int wgid  = (bid & 7) * 196 + (bid >> 3);
  const int ctile = wgid & 1;         // co tile (0/1): co base ctile*128
  const int ptile = wgid >> 1;        // px tile 0..783

  const char* xt_b = (const char*)xt;

  // B staging: 1KB gload = 16 rows x 64B. lane l -> row l>>2, phys chunk l&3.
  // swizzle: LDS[row][phys] holds logical chunk (phys - ((row>>1)&3)) & 3.
  const int lr  = lane >> 2;
  const int sc  = ((((lane & 3) - ((lane >> 3) & 3)) & 3) << 4);

  auto mkB = [&](int jb) -> const char* {
    int px = ptile * 128 + wid * 32 + jb * 16 + lr;
    int b  = px / PIX_PER_IMG;
    int hw = px - b * PIX_PER_IMG;
    int h = hw / WW, w = hw - h * WW;
    return xt_b + (size_t)((b * HP + h) * WP + w) * (CINC * 2) + sc;
  };
  const char* pB0 = mkB(0);
  const char* pB1 = mkB(1);

#define STG(T2, WB) {                                                      \
    int _tap = (T2) >> 3; int _rr = _tap / 3, _ss = _tap - _rr * 3;        \
    size_t _bo = (size_t)(_rr * WP + _ss) * (CINC * 2)                     \
               + (size_t)((T2) & 7) * 64;                                  \
    char* _d = lds + (WB) * BUF_SZ;                                        \
    gload_lds16(pB0 + _bo, _d + wid * 2048 + 0);                           \
    gload_lds16(pB1 + _bo, _d + wid * 2048 + 1024); }

  // A frag loads: frag index (t*16 + mb)*64 + lane; this wave's mb base:
  const frag_t* abase = awr + (size_t)(ctile * 8 + wm * 4) * 64 + lane;

#define ALOAD(T1, FA) {                                                    \
    const frag_t* _p = abase + (size_t)(T1) * (16 * 64);                   \
    _Pragma("unroll") for (int m = 0; m < 4; ++m)                          \
      FA[m] = _p[m * 64]; }

  // B frag reads: row = wn*64 + n*16 + fr -> phys chunk (g + (fr>>1)) & 3
  const int ckr   = (((g + (fr >> 1)) & 3) << 4);
  const int broff = (wn * 64 + fr) * 64 + ckr;

  frag_t fa0[4], fa1[4], fb[4];
  f32x4 acc[4][4] = {};

#define RSL(RB) {                                                          \
    const char* _b = lds + (RB) * BUF_SZ;                                  \
    _Pragma("unroll") for (int n = 0; n < 4; ++n)                          \
      fb[n] = *(const frag_t*)(_b + broff + n * 1024); }

#define MF(FA) {                                                           \
    __builtin_amdgcn_s_setprio(1);                                         \
    _Pragma("unroll") for (int m = 0; m < 4; ++m)                          \
    _Pragma("unroll") for (int n = 0; n < 4; ++n)                          \
      acc[m][n] = __builtin_amdgcn_mfma_f32_16x16x32_bf16(                 \
          FA[m], fb[n], acc[m][n], 0, 0, 0);                               \
    __builtin_amdgcn_s_setprio(0); }

  // body t: stage B(t+3), load A(t+1), read B(t), 16 MFMA.
  // VMEM/body = 2 + 4 = 6. vmcnt(12) = TWO bodies' ops may remain in
  // flight; the stage being enforced (for next body's read) was issued 2
  // bodies (~1600 cy) ago -> HBM/L3 latency fully hidden. Never drains.
#define BODY(T, RB, WB, FCUR, FNXT) {                                      \
    STG((T) + 3, WB);                                                      \
    ALOAD((T) + 1, FNXT);                                                  \
    RSL(RB);                                                               \
    MF(FCUR);                                                              \
    asm volatile("s_waitcnt vmcnt(12)" ::: "memory");                      \
    __builtin_amdgcn_s_barrier();                                          \
    __builtin_amdgcn_sched_barrier(0); }

  // ---- prologue: stage B tiles 0,1,2; load A tile 0
  STG(0, 0);
  STG(1, 1);
  STG(2, 2);
  ALOAD(0, fa0);
  asm volatile("s_waitcnt vmcnt(8)" ::: "memory");   // B(0) landed
  __builtin_amdgcn_s_barrier();
  __builtin_amdgcn_sched_barrier(0);

  // bodies t = 0..67 (17 x 4; ring mod 4, A-parity mod 2)
  for (int base = 0; base < 68; base += 4) {
    BODY(base + 0, 0, 3, fa0, fa1);
    BODY(base + 1, 1, 0, fa1, fa0);
    BODY(base + 2, 2, 1, fa0, fa1);
    BODY(base + 3, 3, 2, fa1, fa0);
  }
  // t = 68: last body that stages (B tile 71 -> buf3)
  {
    STG(71, 3);
    ALOAD(69, fa1);
    RSL(0);
    MF(fa0);
    asm volatile("s_waitcnt vmcnt(12)" ::: "memory");
    __builtin_amdgcn_s_barrier();
    __builtin_amdgcn_sched_barrier(0);
  }
  // t = 69
  {
    ALOAD(70, fa0);
    RSL(1);
    MF(fa1);
    asm volatile("s_waitcnt vmcnt(12)" ::: "memory");
    __builtin_amdgcn_s_barrier();
    __builtin_amdgcn_sched_barrier(0);
  }
  // t = 70: ensure stage(71) retired before next body's read
  {
    ALOAD(71, fa1);
    RSL(2);
    MF(fa0);
    asm volatile("s_waitcnt vmcnt(8)" ::: "memory");
    __builtin_amdgcn_s_barrier();
    __builtin_amdgcn_sched_barrier(0);
  }
  // t = 71
  {
    RSL(3);
    MF(fa1);
  }

  // ---- epilogue: D layout col=lane&15 (px), row=(lane>>4)*4+reg (co)
  int pb[4], phw[4];
#pragma unroll
  for (int n = 0; n < 4; ++n) {
    int pxg = ptile * 128 + wn * 64 + n * 16 + fr;
    pb[n]  = pxg / PIX_PER_IMG;
    phw[n] = pxg - pb[n] * PIX_PER_IMG;
  }
#pragma unroll
  for (int m = 0; m < 4; ++m) {
#pragma unroll
    for (int rg = 0; rg < 4; ++rg) {
      int co = ctile * 128 + wm * 64 + m * 16 + g * 4 + rg;
      float bv = bias[co];
#pragma unroll
      for (int n = 0; n < 4; ++n)
        out[((size_t)pb[n] * COUTC + co) * PIX_PER_IMG + phw[n]] =
            acc[m][n][rg] + bv;
    }
  }
}

// ---------- correctness fallback if workspace is too small
__global__ void conv_direct(const float* __restrict__ inp,
                            const float* __restrict__ kern,
                            const float* __restrict__ bias,
                            float* __restrict__ out) {
  int idx = blockIdx.x * 256 + threadIdx.x;
  if (idx >= BB * COUTC * PIX_PER_IMG) return;
  int w = idx % WW;
  int t = idx / WW;
  int h = t % HH; t /= HH;
  int co = t % COUTC;
  int b  = t / COUTC;
  float acc = bias[co];
  for (int ci = 0; ci < CINC; ++ci)
    for (int r = 0; r < 3; ++r) {
      int hh = h + r - 1;
      if (hh < 0 || hh >= HH) continue;
      for (int s = 0; s < 3; ++s) {
        int ww2 = w + s - 1;
        if (ww2 < 0 || ww2 >= WW) continue;
        acc += inp[((size_t)(b * CINC + ci) * HH + hh) * WW + ww2] *
               kern[(co * CINC + ci) * 9 + r * 3 + s];
      }
    }
  out[idx] = acc;
}

extern "C" void kernel_launch(void* const* d_in, const int* in_sizes, int n_in,
                              void* d_out, int out_size, void* d_ws, size_t ws_size,
                              hipStream_t stream) {
  const float* inp  = (const float*)d_in[0];
  const float* kern = (const float*)d_in[1];
  const float* bias = (const float*)d_in[2];
  float* out = (float*)d_out;

  size_t need = XT_BYTES + AWR_BYTES;
  if (ws_size < need) {
    int tot = BB * COUTC * PIX_PER_IMG;
    conv_direct<<<(tot + 255) / 256, 256, 0, stream>>>(inp, kern, bias, out);
    return;
  }

  __hip_bfloat16* xt = (__hip_bfloat16*)d_ws;
  frag_t* awr = (frag_t*)((char*)d_ws + XT_BYTES);

  xpose_kernel<<<BB * 4 * HP, 256, 0, stream>>>(inp, xt);
  wprep_pack<<<(AWR_FRAGS + 255) / 256, 256, 0, stream>>>(kern, awr);
  conv_ring4<<<2 * (NPIX / 128), 256, 0, stream>>>(xt, awr, bias, out);
}